// Round 15
// baseline (478.161 us; speedup 1.0000x reference)
//
#include <hip/hip_runtime.h>
#include <hip/hip_cooperative_groups.h>
#include <stdint.h>

namespace cg = cooperative_groups;

// ---------------------------------------------------------------------------
// Sampler: scaled = logits/temp ; kth = 50th largest per row ; mask < kth ;
// token = argmax(scaled + gumbel) over survivors, JAX threefry key (0,42).
// VALIDATED R8/R11/R14: partitionable threefry (o0^o1), int32 output,
// radix-select in candidate domain (hist->selbin->compact->finalize),
// absmax 0.0 on hardware.
//
// R15: fuse all phases into ONE cooperative kernel (grid.sync between
// phases). hist writes per-slice partials (no global atomics, no zero
// kernel); selbin sums partials + zeroes candcnt; compact + finalize
// logic byte-identical to validated R14.
// ---------------------------------------------------------------------------
#define SPA   4      // slices per row; grid = B*SPA = 512 blocks (co-resident)
#define MAXC  4096   // candidate capacity per row (expected ~100-300 used)

// ----------------------------- threefry2x32 --------------------------------
__device__ __forceinline__ void tf2x32(uint32_t c0, uint32_t c1,
                                       uint32_t& o0, uint32_t& o1) {
  const uint32_t ks0 = 0u;
  const uint32_t ks1 = 42u;
  const uint32_t ks2 = 0x1BD11BDAu ^ ks0 ^ ks1;
  uint32_t x0 = c0 + ks0;
  uint32_t x1 = c1 + ks1;
#define TF_ROUND(r) { x0 += x1; x1 = (x1 << (r)) | (x1 >> (32 - (r))); x1 ^= x0; }
  TF_ROUND(13) TF_ROUND(15) TF_ROUND(26) TF_ROUND(6)
  x0 += ks1; x1 += ks2 + 1u;
  TF_ROUND(17) TF_ROUND(29) TF_ROUND(16) TF_ROUND(24)
  x0 += ks2; x1 += ks0 + 2u;
  TF_ROUND(13) TF_ROUND(15) TF_ROUND(26) TF_ROUND(6)
  x0 += ks0; x1 += ks1 + 3u;
  TF_ROUND(17) TF_ROUND(29) TF_ROUND(16) TF_ROUND(24)
  x0 += ks1; x1 += ks2 + 4u;
  TF_ROUND(13) TF_ROUND(15) TF_ROUND(26) TF_ROUND(6)
  x0 += ks2; x1 += ks0 + 5u;
#undef TF_ROUND
  o0 = x0; o1 = x1;
}

// partitionable mode (VALIDATED): bits[i] = o0^o1 of threefry((0,42),(0,i))
__device__ __forceinline__ uint32_t jax_bits(uint32_t i) {
  uint32_t o0, o1;
  tf2x32(0u, i, o0, o1);
  return o0 ^ o1;
}

__device__ __forceinline__ float gumbel_from_bits(uint32_t b) {
  float f = __uint_as_float((b >> 9) | 0x3F800000u) - 1.0f;  // [0,1)
  float u = f + 1.17549435e-38f;
  return -logf(-logf(u));
}

// monotone float <-> uint key (ascending order preserved)
__device__ __forceinline__ uint32_t f2key(uint32_t bits) {
  return (bits & 0x80000000u) ? ~bits : (bits | 0x80000000u);
}
__device__ __forceinline__ float key2f(uint32_t key) {
  uint32_t fb = (key & 0x80000000u) ? (key & 0x7FFFFFFFu) : ~key;
  return __uint_as_float(fb);
}

// ------------------------- fused cooperative kernel -------------------------
__global__ __launch_bounds__(256) void fused_sampler(
    const float* __restrict__ logits, const float* __restrict__ temps,
    const int* __restrict__ topk_p, uint32_t* __restrict__ ghist,
    uint32_t* __restrict__ bin12, uint32_t* __restrict__ remk,
    uint32_t* __restrict__ candcnt, uint2* __restrict__ cand,
    int* __restrict__ out, int V) {
  cg::grid_group grid = cg::this_grid();
  const int bid = blockIdx.x;
  const int row = bid / SPA, slice = bid % SPA;
  const int tid = threadIdx.x;
  const float* lrow = logits + (size_t)row * V;
  const float4* l4p = (const float4*)lrow;
  const int n4tot = V >> 2;
  const int s4 = slice * n4tot / SPA;
  const int e4 = (slice + 1) * n4tot / SPA;

  __shared__ uint32_t lh[4096];
  __shared__ uint32_t gsum[64];
  __shared__ uint32_t s_sel, s_rem;
  __shared__ float s_kth;
  __shared__ float swv[4];
  __shared__ int swi[4];

  // ==== phase 1: per-slice 4096-bin histogram -> write partial (no atomics)
  for (int i = tid; i < 4096; i += 256) lh[i] = 0;
  __syncthreads();
  for (int i = s4 + tid; i < e4; i += 256) {
    float4 l4 = l4p[i];
    float lv[4] = {l4.x, l4.y, l4.z, l4.w};
#pragma unroll
    for (int j = 0; j < 4; ++j)
      atomicAdd(&lh[f2key(__float_as_uint(lv[j])) >> 20], 1u);
  }
  if (slice == 0) {  // scalar tail (V % 4)
    for (int v = (n4tot << 2) + tid; v < V; v += 256)
      atomicAdd(&lh[f2key(__float_as_uint(lrow[v])) >> 20], 1u);
  }
  __syncthreads();
  {
    uint32_t* gh = ghist + (size_t)bid * 4096;
    for (int b = tid; b < 4096; b += 256) gh[b] = lh[b];
  }
  __threadfence();
  grid.sync();

  // ==== phase 2: selbin (slice==0 blocks): sum partials, pick bin, zero cnt
  if (slice == 0) {
    for (int b = tid; b < 4096; b += 256) {
      uint32_t s = 0;
#pragma unroll
      for (int p = 0; p < SPA; ++p)
        s += ghist[((size_t)(row * SPA + p)) * 4096 + b];
      lh[b] = s;
    }
    __syncthreads();
    if (tid < 64) {
      uint32_t g = 0;
      for (int j = 0; j < 64; ++j) g += lh[tid * 64 + j];
      gsum[tid] = g;
    }
    __syncthreads();
    if (tid == 0) {
      const uint32_t kk = (uint32_t)(*topk_p);
      uint32_t cum = 0; int g = 63;
      while (g > 0 && cum + gsum[g] < kk) { cum += gsum[g]; --g; }
      int b = g * 64 + 63;
      while (b > g * 64 && cum + lh[b] < kk) { cum += lh[b]; --b; }
      bin12[row] = (uint32_t)b;
      remk[row] = kk - cum;
      candcnt[row] = 0u;
    }
  }
  __threadfence();
  grid.sync();

  // ==== phase 3: compact (key,idx) superset: key >= bin12_edge - 64
  {
    const uint32_t t = bin12[row] << 20;
    const uint32_t lo = (t >= 64u) ? t - 64u : 0u;
    for (int i = s4 + tid; i < e4; i += 256) {
      float4 l4 = l4p[i];
      float lv[4] = {l4.x, l4.y, l4.z, l4.w};
      const int v0 = i * 4;
#pragma unroll
      for (int j = 0; j < 4; ++j) {
        uint32_t key = f2key(__float_as_uint(lv[j]));
        if (key >= lo) {
          uint32_t p = atomicAdd(&candcnt[row], 1u);
          if (p < MAXC) cand[(size_t)row * MAXC + p] = make_uint2(key, (uint32_t)(v0 + j));
        }
      }
    }
    if (slice == 0) {  // scalar tail
      for (int v = (n4tot << 2) + tid; v < V; v += 256) {
        uint32_t key = f2key(__float_as_uint(lrow[v]));
        if (key >= lo) {
          uint32_t p = atomicAdd(&candcnt[row], 1u);
          if (p < MAXC) cand[(size_t)row * MAXC + p] = make_uint2(key, (uint32_t)v);
        }
      }
    }
  }
  __threadfence();
  grid.sync();

  // ==== phase 4: finalize (slice==0): selfin + exact mask + gumbel argmax
  if (slice == 0) {
    const uint32_t n = min(candcnt[row], (uint32_t)MAXC);
    const uint2* cr = cand + (size_t)row * MAXC;
    const uint32_t b12 = bin12[row];

    // pass 1: bits 19:8 among candidates in bin12
    for (int i = tid; i < 4096; i += 256) lh[i] = 0;
    __syncthreads();
    for (uint32_t i = tid; i < n; i += 256) {
      uint32_t k = cr[i].x;
      if ((k >> 20) == b12) atomicAdd(&lh[(k >> 8) & 0xFFFu], 1u);
    }
    __syncthreads();
    if (tid < 64) {
      uint32_t g = 0;
      for (int j = 0; j < 64; ++j) g += lh[tid * 64 + j];
      gsum[tid] = g;
    }
    __syncthreads();
    if (tid == 0) {
      uint32_t kk = remk[row], cum = 0; int g = 63;
      while (g > 0 && cum + gsum[g] < kk) { cum += gsum[g]; --g; }
      int b = g * 64 + 63;
      while (b > g * 64 && cum + lh[b] < kk) { cum += lh[b]; --b; }
      s_sel = (uint32_t)b;
      s_rem = kk - cum;
    }
    __syncthreads();
    const uint32_t sel12 = s_sel;
    const uint32_t kk2 = s_rem;
    __syncthreads();

    // pass 2: low 8 bits among candidates in (b12, sel12)
    for (int i = tid; i < 256; i += 256) lh[i] = 0;
    __syncthreads();
    const uint32_t pre24 = (b12 << 12) | sel12;
    for (uint32_t i = tid; i < n; i += 256) {
      uint32_t k = cr[i].x;
      if ((k >> 8) == pre24) atomicAdd(&lh[k & 0xFFu], 1u);
    }
    __syncthreads();
    if (tid == 0) {
      uint32_t cum = 0; int b = 255;
      while (b > 0 && cum + lh[b] < kk2) { cum += lh[b]; --b; }
      uint32_t kthkey = (b12 << 20) | (sel12 << 8) | (uint32_t)b;
      s_kth = key2f(kthkey) / temps[row];   // identical IEEE op to reference
    }
    __syncthreads();

    // pass 3: reference-exact mask + gumbel argmax over candidates
    const float temp = temps[row];
    const float kth = s_kth;
    const uint32_t rowBase = (uint32_t)(row * V);
    float best = -INFINITY;
    int bestIdx = 0x7FFFFFFF;
    for (uint32_t i = tid; i < n; i += 256) {
      uint2 c = cr[i];
      float s = key2f(c.x) / temp;          // same IEEE div as reference
      if (s < kth) continue;                // exact reference mask
      float g = gumbel_from_bits(jax_bits(rowBase + c.y));
      float val = s + g;
      int idx = (int)c.y;
      if (val > best || (val == best && idx < bestIdx)) { best = val; bestIdx = idx; }
    }
#pragma unroll
    for (int off = 32; off > 0; off >>= 1) {
      float ov = __shfl_down(best, off, 64);
      int oi = __shfl_down(bestIdx, off, 64);
      if (ov > best || (ov == best && oi < bestIdx)) { best = ov; bestIdx = oi; }
    }
    const int wid = tid >> 6;
    const int lane = tid & 63;
    if (lane == 0) { swv[wid] = best; swi[wid] = bestIdx; }
    __syncthreads();
    if (tid == 0) {
      for (int w = 1; w < 4; ++w) {
        if (swv[w] > best || (swv[w] == best && swi[w] < bestIdx)) {
          best = swv[w]; bestIdx = swi[w];
        }
      }
      out[row] = bestIdx;   // int32 token
    }
  }
}

// ---------------------------------------------------------------------------
extern "C" void kernel_launch(void* const* d_in, const int* in_sizes, int n_in,
                              void* d_out, int out_size, void* d_ws, size_t ws_size,
                              hipStream_t stream) {
  const float* logits = (const float*)d_in[0];
  const float* temps  = (const float*)d_in[1];
  const int*   topk   = (const int*)d_in[2];
  const int B = in_sizes[1];
  const int V = in_sizes[0] / B;
  int* out = (int*)d_out;

  // workspace layout (all rewritten every launch; no zero kernel needed)
  uint2*    cand    = (uint2*)d_ws;                          // B*MAXC (8B)
  uint32_t* bin12   = (uint32_t*)(cand + (size_t)B * MAXC);  // B
  uint32_t* remk    = bin12 + B;                             // B
  uint32_t* candcnt = remk + B;                              // B
  uint32_t* ghist   = candcnt + B;                           // B*SPA*4096

  void* args[] = {(void*)&logits, (void*)&temps, (void*)&topk,
                  (void*)&ghist, (void*)&bin12, (void*)&remk,
                  (void*)&candcnt, (void*)&cand, (void*)&out, (void*)&V};
  hipLaunchCooperativeKernel((const void*)fused_sampler,
                             dim3(B * SPA), dim3(256), args, 0, stream);
}